// Round 1
// baseline (416.121 us; speedup 1.0000x reference)
//
#include <hip/hip_runtime.h>
#include <stdint.h>

#define DMODEL 1024
#define NHEADS 16
#define DKH 64
#define BATCH 2
#define SEQ 2048
#define MTOT (BATCH*SEQ)   // 4096

typedef __bf16 bf16x8 __attribute__((ext_vector_type(8)));
typedef float  f32x4  __attribute__((ext_vector_type(4)));

__device__ __forceinline__ f32x4 mfma16(bf16x8 a, bf16x8 b, f32x4 c){
  return __builtin_amdgcn_mfma_f32_16x16x32_bf16(a, b, c, 0, 0, 0);
}

// async global->LDS, 16B per lane. LDS dest must be wave-uniform base; HW lands lane i at base + i*16.
__device__ __forceinline__ void gload_lds16(const void* g, void* l){
  __builtin_amdgcn_global_load_lds(
      (const __attribute__((address_space(1))) uint32_t*)(uintptr_t)g,
      (__attribute__((address_space(3))) uint32_t*)(uint32_t)(uintptr_t)l,
      16, 0, 0);
}

__device__ __forceinline__ unsigned short f2bf(float f){
  unsigned u = __builtin_bit_cast(unsigned, f);
  u += 0x7fff + ((u >> 16) & 1);          // round-to-nearest-even
  return (unsigned short)(u >> 16);
}

// ---------------- fp32 -> bf16 convert ----------------
__global__ void cvt_kernel(const float* __restrict__ in, unsigned short* __restrict__ out, int n4){
  const float4*  in4  = (const float4*)in;
  ushort4*       out4 = (ushort4*)out;
  int i = blockIdx.x * blockDim.x + threadIdx.x;
  int stride = gridDim.x * blockDim.x;
  for (; i < n4; i += stride){
    float4 v = in4[i];
    ushort4 o;
    o.x = f2bf(v.x); o.y = f2bf(v.y); o.z = f2bf(v.z); o.w = f2bf(v.w);
    out4[i] = o;
  }
}

// ---------------- GEMM: C[m,n] = sum_k A[m,k]*B[n,k]  (B^T layout) ----------------
// EPI==0: scatter to Q[b,h,s,dk], K[b,h,s,dk], Vt[b,h,dk,s] (bf16)
// EPI==1: plain fp32 store to Co[m*N + n]
template<int EPI>
__global__ __launch_bounds__(256)
void gemm_bt(const __bf16* __restrict__ Ag, const __bf16* __restrict__ Bg,
             int M, int N, int K,
             __bf16* __restrict__ Qo, __bf16* __restrict__ Ko, __bf16* __restrict__ Vt,
             float* __restrict__ Co){
  __shared__ __align__(16) __bf16 As[128*32];
  __shared__ __align__(16) __bf16 Bs[128*32];
  const int tid  = threadIdx.x;
  const int wave = tid >> 6, lane = tid & 63;
  const int wr = wave >> 1, wc = wave & 1;
  const int lr = lane & 15, lg = lane >> 4;
  const int m0 = blockIdx.y * 128, n0 = blockIdx.x * 128;

  f32x4 acc[4][4] = {};

  const int srow = lane >> 2;        // 0..15
  const int scol = (lane & 3) * 8;   // 0,8,16,24
  const __bf16* gA = Ag + (size_t)(m0 + wave*32 + srow) * K + scol;
  const __bf16* gB = Bg + (size_t)(n0 + wave*32 + srow) * K + scol;
  __bf16* lA = &As[(wave*32) * 32];
  __bf16* lB = &Bs[(wave*32) * 32];

  for (int k0 = 0; k0 < K; k0 += 32){
    __syncthreads();                       // prior compute done before overwrite
    gload_lds16(gA + k0,                lA);
    gload_lds16(gA + k0 + (size_t)16*K, lA + 16*32);
    gload_lds16(gB + k0,                lB);
    gload_lds16(gB + k0 + (size_t)16*K, lB + 16*32);
    __syncthreads();                       // staging drained (compiler emits vmcnt(0))

    bf16x8 af[4], bfv[4];
#pragma unroll
    for (int i = 0; i < 4; i++)
      af[i] = *(const bf16x8*)&As[(wr*64 + i*16 + lr)*32 + lg*8];
#pragma unroll
    for (int j = 0; j < 4; j++)
      bfv[j] = *(const bf16x8*)&Bs[(wc*64 + j*16 + lr)*32 + lg*8];
#pragma unroll
    for (int i = 0; i < 4; i++)
#pragma unroll
      for (int j = 0; j < 4; j++)
        acc[i][j] = mfma16(af[i], bfv[j], acc[i][j]);
  }

  if (EPI == 0){
    const int three = n0 >> 10;            // block-uniform (128 | 1024)
#pragma unroll
    for (int i = 0; i < 4; i++){
#pragma unroll
      for (int j = 0; j < 4; j++){
#pragma unroll
        for (int r = 0; r < 4; r++){
          int m = m0 + wr*64 + i*16 + lg*4 + r;     // C row
          int n = n0 + wc*64 + j*16 + lr;           // C col
          int b = m >> 11, s = m & 2047;
          int h = (n >> 6) & 15, dk = n & 63;
          __bf16 val = (__bf16)acc[i][j][r];
          if (three == 0)      Qo[(((size_t)(b*NHEADS + h))*SEQ + s)*DKH + dk] = val;
          else if (three == 1) Ko[(((size_t)(b*NHEADS + h))*SEQ + s)*DKH + dk] = val;
          else                 Vt[(((size_t)(b*NHEADS + h))*DKH + dk)*SEQ + s] = val;
        }
      }
    }
  } else {
#pragma unroll
    for (int i = 0; i < 4; i++)
#pragma unroll
      for (int j = 0; j < 4; j++)
#pragma unroll
        for (int r = 0; r < 4; r++){
          int m = m0 + wr*64 + i*16 + lg*4 + r;
          int n = n0 + wc*64 + j*16 + lr;
          Co[(size_t)m * N + n] = acc[i][j][r];
        }
  }
}

// ---------------- causal flash attention ----------------
// Q,K: [b,h,s,dk] bf16; Vt: [b,h,dk,s] bf16; Aout: [b,s,h*64+dk] bf16
__global__ __launch_bounds__(256)
void attn_kernel(const __bf16* __restrict__ Q, const __bf16* __restrict__ K,
                 const __bf16* __restrict__ Vt, __bf16* __restrict__ Aout){
  const int qblk = gridDim.x - 1 - blockIdx.x;   // heavy blocks first
  const int bh   = blockIdx.y;
  const int wave = threadIdx.x >> 6, lane = threadIdx.x & 63;
  const int lr = lane & 15, lg = lane >> 4;
  const int qw = qblk*64 + wave*16;              // wave's first q row

  const __bf16* Qh = Q  + (size_t)bh * SEQ * DKH;
  const __bf16* Kh = K  + (size_t)bh * SEQ * DKH;
  const __bf16* Vh = Vt + (size_t)bh * DKH * SEQ;

  __shared__ __align__(16) __bf16 Plds[4][16][72];   // 72-elem stride: 144B, 16B-aligned rows
  __bf16 (*Pw)[72] = Plds[wave];

  bf16x8 qf0 = *(const bf16x8*)(Qh + (size_t)(qw + lr)*DKH + lg*8);
  bf16x8 qf1 = *(const bf16x8*)(Qh + (size_t)(qw + lr)*DKH + 32 + lg*8);

  f32x4 o[4] = {};
  float mrun[4], lrun[4];
#pragma unroll
  for (int r = 0; r < 4; r++){ mrun[r] = -1e30f; lrun[r] = 0.f; }

  const float k2 = 0.125f * 1.44269504088896340736f;   // scale * log2(e)
  const int nkv = (qw + 15)/64 + 1;

  for (int kb = 0; kb < nkv; kb++){
    const int kv0 = kb * 64;
    f32x4 sf[4];
#pragma unroll
    for (int t = 0; t < 4; t++){
      const __bf16* kp = Kh + (size_t)(kv0 + t*16 + lr)*DKH + lg*8;
      bf16x8 kf0 = *(const bf16x8*)kp;
      bf16x8 kf1 = *(const bf16x8*)(kp + 32);
      f32x4 c = {};
      c = mfma16(qf0, kf0, c);
      c = mfma16(qf1, kf1, c);
      sf[t] = c;
    }
    if ((kv0 + 63) > qw){       // masked tile
#pragma unroll
      for (int t = 0; t < 4; t++){
        int kv = kv0 + t*16 + lr;
#pragma unroll
        for (int r = 0; r < 4; r++){
          int q = qw + lg*4 + r;
          sf[t][r] = (kv <= q) ? sf[t][r]*k2 : -1e30f;
        }
      }
    } else {
#pragma unroll
      for (int t = 0; t < 4; t++)
#pragma unroll
        for (int r = 0; r < 4; r++)
          sf[t][r] *= k2;
    }
    // row max: over 4 kv-tiles then across the 16 col-lanes
    f32x4 mx = sf[0];
#pragma unroll
    for (int t = 1; t < 4; t++)
#pragma unroll
      for (int r = 0; r < 4; r++) mx[r] = fmaxf(mx[r], sf[t][r]);
#pragma unroll
    for (int d = 1; d < 16; d <<= 1)
#pragma unroll
      for (int r = 0; r < 4; r++)
        mx[r] = fmaxf(mx[r], __shfl_xor(mx[r], d));

    float alpha[4];
#pragma unroll
    for (int r = 0; r < 4; r++){
      float mn = fmaxf(mrun[r], mx[r]);
      alpha[r] = exp2f(mrun[r] - mn);
      mrun[r] = mn;
      lrun[r] *= alpha[r];
    }
#pragma unroll
    for (int n = 0; n < 4; n++)
#pragma unroll
      for (int r = 0; r < 4; r++)
        o[n][r] *= alpha[r];

    // P = exp2(s - m), per-lane partial row sums, stage P (C-layout -> [q][kv])
#pragma unroll
    for (int t = 0; t < 4; t++){
#pragma unroll
      for (int r = 0; r < 4; r++){
        float p = exp2f(sf[t][r] - mrun[r]);
        lrun[r] += p;
        Pw[lg*4 + r][t*16 + lr] = (__bf16)p;
      }
    }
    // PV: A = P from LDS (A-frag layout), B = Vt rows (contiguous 16B/lane)
#pragma unroll
    for (int ks = 0; ks < 2; ks++){
      bf16x8 pa = *(const bf16x8*)&Pw[lr][ks*32 + lg*8];
#pragma unroll
      for (int n = 0; n < 4; n++){
        bf16x8 vf = *(const bf16x8*)(Vh + (size_t)(n*16 + lr)*SEQ + kv0 + ks*32 + lg*8);
        o[n] = mfma16(pa, vf, o[n]);
      }
    }
  }

  // finish: reduce partial row sums across the 16 col-lanes
#pragma unroll
  for (int d = 1; d < 16; d <<= 1)
#pragma unroll
    for (int r = 0; r < 4; r++)
      lrun[r] += __shfl_xor(lrun[r], d);

  const int b = bh >> 4, h = bh & 15;
#pragma unroll
  for (int r = 0; r < 4; r++){
    float inv = 1.0f / lrun[r];
    int q = qw + lg*4 + r;
    __bf16* dst = Aout + ((size_t)b*SEQ + q)*DMODEL + h*DKH;
#pragma unroll
    for (int n = 0; n < 4; n++)
      dst[n*16 + lr] = (__bf16)(o[n][r] * inv);
  }
}

// ---------------- launch ----------------
extern "C" void kernel_launch(void* const* d_in, const int* in_sizes, int n_in,
                              void* d_out, int out_size, void* d_ws, size_t ws_size,
                              hipStream_t stream){
  const float* x    = (const float*)d_in[0];
  const float* wqkv = (const float*)d_in[1];
  const float* wout = (const float*)d_in[2];
  float* out = (float*)d_out;
  char* ws = (char*)d_ws;

  // workspace layout (bytes); Ab aliases xb (xb dead after QKV GEMM)
  __bf16* xb  = (__bf16*)(ws);                    //  8,388,608  x bf16 [4096,1024]
  __bf16* Ab  = (__bf16*)(ws);                    //  attn out bf16 [4096,1024] (alias)
  __bf16* wqb = (__bf16*)(ws + 8388608);          //  6,291,456  W_qkv bf16 [3072,1024]
  __bf16* wob = (__bf16*)(ws + 14680064);         //  2,097,152  W_out bf16 [1024,1024]
  __bf16* Qb  = (__bf16*)(ws + 16777216);         //  8,388,608  Q [b,h,s,dk]
  __bf16* Kb  = (__bf16*)(ws + 25165824);         //  8,388,608  K [b,h,s,dk]
  __bf16* Vtb = (__bf16*)(ws + 33554432);         //  8,388,608  V^T [b,h,dk,s]
  // total 41,943,040 bytes

  cvt_kernel<<<1024, 256, 0, stream>>>(x,    (unsigned short*)xb,  (MTOT*DMODEL)/4);
  cvt_kernel<<<1024, 256, 0, stream>>>(wqkv, (unsigned short*)wqb, (3*DMODEL*DMODEL)/4);
  cvt_kernel<<<256,  256, 0, stream>>>(wout, (unsigned short*)wob, (DMODEL*DMODEL)/4);

  gemm_bt<0><<<dim3(24, 32), 256, 0, stream>>>(xb, wqb, MTOT, 3*DMODEL, DMODEL,
                                               Qb, Kb, Vtb, nullptr);
  attn_kernel<<<dim3(32, 32), 256, 0, stream>>>(Qb, Kb, Vtb, Ab);
  gemm_bt<1><<<dim3(8, 32), 256, 0, stream>>>(Ab, wob, MTOT, DMODEL, DMODEL,
                                              nullptr, nullptr, nullptr, out);
}

// Round 2
// 294.459 us; speedup vs baseline: 1.4132x; 1.4132x over previous
//
#include <hip/hip_runtime.h>
#include <stdint.h>

#define DMODEL 1024
#define NHEADS 16
#define DKH 64
#define BATCH 2
#define SEQ 2048
#define MTOT (BATCH*SEQ)   // 4096

typedef __bf16 bf16x8 __attribute__((ext_vector_type(8)));
typedef float  f32x4  __attribute__((ext_vector_type(4)));

__device__ __forceinline__ f32x4 mfma16(bf16x8 a, bf16x8 b, f32x4 c){
  return __builtin_amdgcn_mfma_f32_16x16x32_bf16(a, b, c, 0, 0, 0);
}

// async global->LDS, 16B per lane. LDS dest must be wave-uniform base; HW lands lane i at base + i*16.
__device__ __forceinline__ void gload_lds16(const void* g, void* l){
  __builtin_amdgcn_global_load_lds(
      (const __attribute__((address_space(1))) uint32_t*)(uintptr_t)g,
      (__attribute__((address_space(3))) uint32_t*)(uint32_t)(uintptr_t)l,
      16, 0, 0);
}

__device__ __forceinline__ unsigned short f2bf(float f){
  unsigned u = __builtin_bit_cast(unsigned, f);
  u += 0x7fff + ((u >> 16) & 1);          // round-to-nearest-even
  return (unsigned short)(u >> 16);
}

// ---------------- fp32 -> bf16 convert ----------------
__global__ void cvt_kernel(const float* __restrict__ in, unsigned short* __restrict__ out, int n4){
  const float4*  in4  = (const float4*)in;
  ushort4*       out4 = (ushort4*)out;
  int i = blockIdx.x * blockDim.x + threadIdx.x;
  int stride = gridDim.x * blockDim.x;
  for (; i < n4; i += stride){
    float4 v = in4[i];
    ushort4 o;
    o.x = f2bf(v.x); o.y = f2bf(v.y); o.z = f2bf(v.z); o.w = f2bf(v.w);
    out4[i] = o;
  }
}

// ---------------- GEMM: C[m,n] = sum_k A[m,k]*B[n,k]  (B^T layout) ----------------
// EPI==0: scatter to Q[b,h,s,dk], K[b,h,s,dk], Vt[b,h,dk,s] (bf16)
// EPI==1: plain fp32 store to Co[m*N + n]
template<int EPI>
__global__ __launch_bounds__(256)
void gemm_bt(const __bf16* __restrict__ Ag, const __bf16* __restrict__ Bg,
             int M, int N, int K,
             __bf16* __restrict__ Qo, __bf16* __restrict__ Ko, __bf16* __restrict__ Vt,
             float* __restrict__ Co){
  __shared__ __align__(16) __bf16 As[128*32];
  __shared__ __align__(16) __bf16 Bs[128*32];
  const int tid  = threadIdx.x;
  const int wave = tid >> 6, lane = tid & 63;
  const int wr = wave >> 1, wc = wave & 1;
  const int lr = lane & 15, lg = lane >> 4;
  const int m0 = blockIdx.y * 128, n0 = blockIdx.x * 128;

  f32x4 acc[4][4] = {};

  const int srow = lane >> 2;        // 0..15
  const int scol = (lane & 3) * 8;   // 0,8,16,24
  const __bf16* gA = Ag + (size_t)(m0 + wave*32 + srow) * K + scol;
  const __bf16* gB = Bg + (size_t)(n0 + wave*32 + srow) * K + scol;
  __bf16* lA = &As[(wave*32) * 32];
  __bf16* lB = &Bs[(wave*32) * 32];

  for (int k0 = 0; k0 < K; k0 += 32){
    __syncthreads();                       // prior compute done before overwrite
    gload_lds16(gA + k0,                lA);
    gload_lds16(gA + k0 + (size_t)16*K, lA + 16*32);
    gload_lds16(gB + k0,                lB);
    gload_lds16(gB + k0 + (size_t)16*K, lB + 16*32);
    __syncthreads();                       // staging drained (compiler emits vmcnt(0))

    bf16x8 af[4], bfv[4];
#pragma unroll
    for (int i = 0; i < 4; i++)
      af[i] = *(const bf16x8*)&As[(wr*64 + i*16 + lr)*32 + lg*8];
#pragma unroll
    for (int j = 0; j < 4; j++)
      bfv[j] = *(const bf16x8*)&Bs[(wc*64 + j*16 + lr)*32 + lg*8];
#pragma unroll
    for (int i = 0; i < 4; i++)
#pragma unroll
      for (int j = 0; j < 4; j++)
        acc[i][j] = mfma16(af[i], bfv[j], acc[i][j]);
  }

  if (EPI == 0){
    const int three = n0 >> 10;            // block-uniform (128 | 1024)
#pragma unroll
    for (int i = 0; i < 4; i++){
#pragma unroll
      for (int j = 0; j < 4; j++){
#pragma unroll
        for (int r = 0; r < 4; r++){
          int m = m0 + wr*64 + i*16 + lg*4 + r;     // C row
          int n = n0 + wc*64 + j*16 + lr;           // C col
          int b = m >> 11, s = m & 2047;
          int h = (n >> 6) & 15, dk = n & 63;
          __bf16 val = (__bf16)acc[i][j][r];
          if (three == 0)      Qo[(((size_t)(b*NHEADS + h))*SEQ + s)*DKH + dk] = val;
          else if (three == 1) Ko[(((size_t)(b*NHEADS + h))*SEQ + s)*DKH + dk] = val;
          else                 Vt[(((size_t)(b*NHEADS + h))*DKH + dk)*SEQ + s] = val;
        }
      }
    }
  } else {
#pragma unroll
    for (int i = 0; i < 4; i++)
#pragma unroll
      for (int j = 0; j < 4; j++)
#pragma unroll
        for (int r = 0; r < 4; r++){
          int m = m0 + wr*64 + i*16 + lg*4 + r;
          int n = n0 + wc*64 + j*16 + lr;
          Co[(size_t)m * N + n] = acc[i][j][r];
        }
  }
}

// ---------------- causal flash attention ----------------
// Q,K: [b,h,s,dk] bf16; Vt: [b,h,dk,s] bf16; Aout: [b,s,h*64+dk] bf16
// Causal load balancing: 64 q-tiles of 32 rows; block j handles pair (j, 63-j).
// Waves 0,1 -> tile j (rows j*32 + {0,16}); waves 2,3 -> tile 63-j.
// Every block does a constant ~66 wave-iters -> uniform work per CU.
__global__ __launch_bounds__(256)
void attn_kernel(const __bf16* __restrict__ Q, const __bf16* __restrict__ K,
                 const __bf16* __restrict__ Vt, __bf16* __restrict__ Aout){
  const int j    = blockIdx.x;                   // pair index 0..31
  const int bh   = blockIdx.y;
  const int wave = threadIdx.x >> 6, lane = threadIdx.x & 63;
  const int lr = lane & 15, lg = lane >> 4;
  const int tile = (wave < 2) ? j : (63 - j);    // 32-row q-tile index
  const int qw   = tile*32 + (wave & 1)*16;      // wave's first q row

  const __bf16* Qh = Q  + (size_t)bh * SEQ * DKH;
  const __bf16* Kh = K  + (size_t)bh * SEQ * DKH;
  const __bf16* Vh = Vt + (size_t)bh * DKH * SEQ;

  __shared__ __align__(16) __bf16 Plds[4][16][72];   // 72-elem stride: 144B, 16B-aligned rows
  __bf16 (*Pw)[72] = Plds[wave];

  bf16x8 qf0 = *(const bf16x8*)(Qh + (size_t)(qw + lr)*DKH + lg*8);
  bf16x8 qf1 = *(const bf16x8*)(Qh + (size_t)(qw + lr)*DKH + 32 + lg*8);

  f32x4 o[4] = {};
  float mrun[4], lrun[4];
#pragma unroll
  for (int r = 0; r < 4; r++){ mrun[r] = -1e30f; lrun[r] = 0.f; }

  const float k2 = 0.125f * 1.44269504088896340736f;   // scale * log2(e)
  const int nkv = (qw + 15)/64 + 1;

  for (int kb = 0; kb < nkv; kb++){
    const int kv0 = kb * 64;
    f32x4 sf[4];
#pragma unroll
    for (int t = 0; t < 4; t++){
      const __bf16* kp = Kh + (size_t)(kv0 + t*16 + lr)*DKH + lg*8;
      bf16x8 kf0 = *(const bf16x8*)kp;
      bf16x8 kf1 = *(const bf16x8*)(kp + 32);
      f32x4 c = {};
      c = mfma16(qf0, kf0, c);
      c = mfma16(qf1, kf1, c);
      sf[t] = c;
    }
    // hoist ks=0 V fragments above the softmax chain (latency hiding, +32 VGPR)
    bf16x8 vf0[4];
#pragma unroll
    for (int n = 0; n < 4; n++)
      vf0[n] = *(const bf16x8*)(Vh + (size_t)(n*16 + lr)*SEQ + kv0 + lg*8);

    if ((kv0 + 63) > qw){       // masked tile
#pragma unroll
      for (int t = 0; t < 4; t++){
        int kv = kv0 + t*16 + lr;
#pragma unroll
        for (int r = 0; r < 4; r++){
          int q = qw + lg*4 + r;
          sf[t][r] = (kv <= q) ? sf[t][r]*k2 : -1e30f;
        }
      }
    } else {
#pragma unroll
      for (int t = 0; t < 4; t++)
#pragma unroll
        for (int r = 0; r < 4; r++)
          sf[t][r] *= k2;
    }
    // row max: over 4 kv-tiles then across the 16 col-lanes
    f32x4 mx = sf[0];
#pragma unroll
    for (int t = 1; t < 4; t++)
#pragma unroll
      for (int r = 0; r < 4; r++) mx[r] = fmaxf(mx[r], sf[t][r]);
#pragma unroll
    for (int d = 1; d < 16; d <<= 1)
#pragma unroll
      for (int r = 0; r < 4; r++)
        mx[r] = fmaxf(mx[r], __shfl_xor(mx[r], d));

    float alpha[4];
#pragma unroll
    for (int r = 0; r < 4; r++){
      float mn = fmaxf(mrun[r], mx[r]);
      alpha[r] = __builtin_amdgcn_exp2f(mrun[r] - mn);
      mrun[r] = mn;
      lrun[r] *= alpha[r];
    }
#pragma unroll
    for (int n = 0; n < 4; n++)
#pragma unroll
      for (int r = 0; r < 4; r++)
        o[n][r] *= alpha[r];

    // P = exp2(s - m), per-lane partial row sums, stage P (C-layout -> [q][kv])
#pragma unroll
    for (int t = 0; t < 4; t++){
#pragma unroll
      for (int r = 0; r < 4; r++){
        float p = __builtin_amdgcn_exp2f(sf[t][r] - mrun[r]);
        lrun[r] += p;
        Pw[lg*4 + r][t*16 + lr] = (__bf16)p;
      }
    }
    // PV: A = P from LDS (A-frag layout), B = Vt rows (contiguous 16B/lane)
    {
      bf16x8 pa0 = *(const bf16x8*)&Pw[lr][lg*8];
#pragma unroll
      for (int n = 0; n < 4; n++)
        o[n] = mfma16(pa0, vf0[n], o[n]);
      bf16x8 pa1 = *(const bf16x8*)&Pw[lr][32 + lg*8];
#pragma unroll
      for (int n = 0; n < 4; n++){
        bf16x8 vf = *(const bf16x8*)(Vh + (size_t)(n*16 + lr)*SEQ + kv0 + 32 + lg*8);
        o[n] = mfma16(pa1, vf, o[n]);
      }
    }
  }

  // finish: reduce partial row sums across the 16 col-lanes
#pragma unroll
  for (int d = 1; d < 16; d <<= 1)
#pragma unroll
    for (int r = 0; r < 4; r++)
      lrun[r] += __shfl_xor(lrun[r], d);

  const int b = bh >> 4, h = bh & 15;
#pragma unroll
  for (int r = 0; r < 4; r++){
    float inv = 1.0f / lrun[r];
    int q = qw + lg*4 + r;
    __bf16* dst = Aout + ((size_t)b*SEQ + q)*DMODEL + h*DKH;
#pragma unroll
    for (int n = 0; n < 4; n++)
      dst[n*16 + lr] = (__bf16)(o[n][r] * inv);
  }
}

// ---------------- launch ----------------
extern "C" void kernel_launch(void* const* d_in, const int* in_sizes, int n_in,
                              void* d_out, int out_size, void* d_ws, size_t ws_size,
                              hipStream_t stream){
  const float* x    = (const float*)d_in[0];
  const float* wqkv = (const float*)d_in[1];
  const float* wout = (const float*)d_in[2];
  float* out = (float*)d_out;
  char* ws = (char*)d_ws;

  // workspace layout (bytes); Ab aliases xb (xb dead after QKV GEMM)
  __bf16* xb  = (__bf16*)(ws);                    //  8,388,608  x bf16 [4096,1024]
  __bf16* Ab  = (__bf16*)(ws);                    //  attn out bf16 [4096,1024] (alias)
  __bf16* wqb = (__bf16*)(ws + 8388608);          //  6,291,456  W_qkv bf16 [3072,1024]
  __bf16* wob = (__bf16*)(ws + 14680064);         //  2,097,152  W_out bf16 [1024,1024]
  __bf16* Qb  = (__bf16*)(ws + 16777216);         //  8,388,608  Q [b,h,s,dk]
  __bf16* Kb  = (__bf16*)(ws + 25165824);         //  8,388,608  K [b,h,s,dk]
  __bf16* Vtb = (__bf16*)(ws + 33554432);         //  8,388,608  V^T [b,h,dk,s]
  // total 41,943,040 bytes

  cvt_kernel<<<1024, 256, 0, stream>>>(x,    (unsigned short*)xb,  (MTOT*DMODEL)/4);
  cvt_kernel<<<1024, 256, 0, stream>>>(wqkv, (unsigned short*)wqb, (3*DMODEL*DMODEL)/4);
  cvt_kernel<<<256,  256, 0, stream>>>(wout, (unsigned short*)wob, (DMODEL*DMODEL)/4);

  gemm_bt<0><<<dim3(24, 32), 256, 0, stream>>>(xb, wqb, MTOT, 3*DMODEL, DMODEL,
                                               Qb, Kb, Vtb, nullptr);
  attn_kernel<<<dim3(32, 32), 256, 0, stream>>>(Qb, Kb, Vtb, Ab);
  gemm_bt<1><<<dim3(8, 32), 256, 0, stream>>>(Ab, wob, MTOT, DMODEL, DMODEL,
                                              nullptr, nullptr, nullptr, out);
}